// Round 2
// baseline (668.903 us; speedup 1.0000x reference)
//
#include <hip/hip_runtime.h>
#include <math.h>

// BarrierNet fused forward: MLP (8->256->128->2 twice) + closed-form 2D QP.
// ALL tensors are float32 (reference uses jnp.float32 throughout).

// Fused layer2 (256->128, relu) + layer3 (128->2): o = W3 @ relu(W2 @ hid + b2) + b3
__device__ __forceinline__ void head(const float* __restrict__ W2,   // [128][256]
                                     const float* __restrict__ b2,   // [128]
                                     const float* __restrict__ W3,   // [2][128]
                                     const float* __restrict__ b3,   // [2]
                                     const float (&hid)[256],
                                     float& o0, float& o1)
{
    float p0 = b3[0];
    float p1 = b3[1];
    for (int i = 0; i < 128; ++i) {
        const float* w = W2 + i * 256;
        float a0 = b2[i], a1 = 0.f, a2 = 0.f, a3 = 0.f;
        #pragma unroll
        for (int k = 0; k < 256; k += 4) {
            a0 = fmaf(w[k],     hid[k],     a0);
            a1 = fmaf(w[k + 1], hid[k + 1], a1);
            a2 = fmaf(w[k + 2], hid[k + 2], a2);
            a3 = fmaf(w[k + 3], hid[k + 3], a3);
        }
        float rj = fmaxf((a0 + a1) + (a2 + a3), 0.f);
        p0 = fmaf(rj, W3[i],       p0);
        p1 = fmaf(rj, W3[128 + i], p1);
    }
    o0 = p0; o1 = p1;
}

__global__ __launch_bounds__(64)
void barriernet_kernel(const float* __restrict__ x,      // [B,8]
                       const float* __restrict__ meanp,  // [8]
                       const float* __restrict__ stdp,   // [8]
                       const float* __restrict__ W1,     // [256][8]
                       const float* __restrict__ b1,     // [256]
                       const float* __restrict__ W21,    // [128][256]
                       const float* __restrict__ b21,    // [128]
                       const float* __restrict__ W31,    // [2][128]
                       const float* __restrict__ b31,    // [2]
                       const float* __restrict__ W22,    // [128][256]
                       const float* __restrict__ b22,    // [128]
                       const float* __restrict__ W32,    // [2][128]
                       const float* __restrict__ b32,    // [2]
                       float* __restrict__ out, int B)
{
    int r = blockIdx.x * blockDim.x + threadIdx.x;
    if (r >= B) return;

    // ---- load input row
    float xf[8];
    const float* xp = x + r * 8;
    #pragma unroll
    for (int k = 0; k < 8; ++k) xf[k] = xp[k];

    // ---- layer 1: hid = relu(x @ W1.T + b1), f32 in registers
    float hid[256];
    #pragma unroll
    for (int j = 0; j < 256; ++j) {
        const float* w = W1 + j * 8;
        float a = b1[j];
        #pragma unroll
        for (int k = 0; k < 8; ++k) a = fmaf(w[k], xf[k], a);
        hid[j] = fmaxf(a, 0.f);
    }

    // ---- two heads
    float p0, p1;                 // x31 = QP linear term p
    head(W21, b21, W31, b31, hid, p0, p1);
    float t0, t1;
    head(W22, b22, W32, b32, hid, t0, t1);
    float s0 = 4.f / (1.f + expf(-t0));
    float s1 = 4.f / (1.f + expf(-t1));

    // ---- physical state x0 = x*std + mean
    float x0v[8];
    #pragma unroll
    for (int k = 0; k < 8; ++k)
        x0v[k] = fmaf(xf[k], stdp[k], meanp[k]);
    float px = x0v[0], py = x0v[1], th = x0v[2], v = x0v[3];
    float ox = x0v[4], oy = x0v[5], oth = x0v[6], ov = x0v[7];

    float st = sinf(th),  ct = cosf(th);
    float so = sinf(oth), co = cosf(oth);
    float vs = v * st, vc = v * ct;
    float sps = s0 + s1, ss = s0 * s1;

    // ---- constraints G z <= h (8 obstacles + 1 opponent)
    const float obx[8] = { 10.f, 7.07106781186547524f, 6.123234e-16f, -7.07106781186547524f,
                          -10.f, -7.07106781186547524f, -1.8369702e-15f, 7.07106781186547524f };
    const float oby[8] = { 0.f, 7.07106781186547524f, 10.f, 7.07106781186547524f,
                           1.2246468e-15f, -7.07106781186547524f, -10.f, -7.07106781186547524f };
    float Gx[9], Gy[9], hc[9], tol[9];
    float Lf2b = 2.f * v * v;
    #pragma unroll
    for (int k = 0; k < 8; ++k) {
        float dx = px - obx[k], dy = py - oby[k];
        float bar  = dx * dx + dy * dy - 0.64f;          // R=0.8
        float bdot = 2.f * dx * vc + 2.f * dy * vs;
        float u1 = -2.f * dx * vs + 2.f * dy * vc;
        float u2 =  2.f * dx * ct + 2.f * dy * st;
        Gx[k] = -u1; Gy[k] = -u2;
        hc[k] = Lf2b + sps * bdot + ss * bar;
    }
    {
        float dxo = px - ox, dyo = py - oy;
        float bar_o  = dxo * dxo + dyo * dyo - 0.25f;    // Ro=0.5
        float bdot_o = 2.f * dxo * (vc - ov * co) + 2.f * dyo * (vs - ov * so);
        float Lf2b_o = 2.f * (v * v + ov * ov + 2.f * v * ov * cosf(th - oth));
        float u1o = -2.f * dxo * vs + 2.f * dyo * vc;
        float u2o =  2.f * dxo * ct + 2.f * dyo * st;
        Gx[8] = -u1o; Gy[8] = -u2o;
        hc[8] = Lf2b_o + sps * bdot_o + ss * bar_o;
    }
    #pragma unroll
    for (int k = 0; k < 9; ++k) tol[k] = 1e-6f * (1.f + fabsf(hc[k]));

    // ---- QP: min 0.5|z|^2 + p.z  s.t. Gz<=h ; enumerate active sets 0/1/2
    float bzx = -p0, bzy = -p1;          // Z[0] fallback (argmin of all-inf -> idx 0)
    float bobj = INFINITY;
    {   // candidate 0 (unconstrained)
        float zx = -p0, zy = -p1;
        bool f = true;
        #pragma unroll
        for (int k = 0; k < 9; ++k) f = f && (zx * Gx[k] + zy * Gy[k] <= hc[k] + tol[k]);
        if (f) bobj = 0.5f * (zx * zx + zy * zy) + zx * p0 + zy * p1;
    }
    // singles, i = 0..8 (order matters: first-min tie-break)
    #pragma unroll
    for (int i = 0; i < 9; ++i) {
        float gg  = Gx[i] * Gx[i] + Gy[i] * Gy[i];
        float lam = (-(Gx[i] * p0 + Gy[i] * p1) - hc[i]) / (gg + 1e-12f);
        float zx = -p0 - lam * Gx[i];
        float zy = -p1 - lam * Gy[i];
        bool ok = (lam >= -1e-8f);
        #pragma unroll
        for (int k = 0; k < 9; ++k) ok = ok && (zx * Gx[k] + zy * Gy[k] <= hc[k] + tol[k]);
        float obj = 0.5f * (zx * zx + zy * zy) + zx * p0 + zy * p1;
        if (ok && obj < bobj) { bobj = obj; bzx = zx; bzy = zy; }
    }
    // pairs, triu order (0,1),(0,2)..(0,8),(1,2)..
    #pragma unroll
    for (int i = 0; i < 8; ++i) {
        #pragma unroll
        for (int j = i + 1; j < 9; ++j) {
            float det = Gx[i] * Gy[j] - Gy[i] * Gx[j];
            bool dok = fabsf(det) > 1e-9f;
            float ds = dok ? det : 1.0f;
            float zx = (hc[i] * Gy[j] - hc[j] * Gy[i]) / ds;
            float zy = (Gx[i] * hc[j] - Gx[j] * hc[i]) / ds;
            float rx = -(zx + p0), ry = -(zy + p1);
            float li = (Gy[j] * rx - Gx[j] * ry) / ds;
            float lj = (Gx[i] * ry - Gy[i] * rx) / ds;
            bool ok = dok && (li >= -1e-8f) && (lj >= -1e-8f);
            #pragma unroll
            for (int k = 0; k < 9; ++k) ok = ok && (zx * Gx[k] + zy * Gy[k] <= hc[k] + tol[k]);
            float obj = 0.5f * (zx * zx + zy * zy) + zx * p0 + zy * p1;
            if (ok && obj < bobj) { bobj = obj; bzx = zx; bzy = zy; }
        }
    }

    out[2 * r]     = bzx;
    out[2 * r + 1] = bzy;
}

extern "C" void kernel_launch(void* const* d_in, const int* in_sizes, int n_in,
                              void* d_out, int out_size, void* d_ws, size_t ws_size,
                              hipStream_t stream) {
    const float* x    = (const float*)d_in[0];
    const float* mean = (const float*)d_in[1];
    const float* stdv = (const float*)d_in[2];
    const float* W1   = (const float*)d_in[3];
    const float* b1   = (const float*)d_in[4];
    const float* W21  = (const float*)d_in[5];
    const float* b21  = (const float*)d_in[6];
    const float* W31  = (const float*)d_in[7];
    const float* b31  = (const float*)d_in[8];
    const float* W22  = (const float*)d_in[9];
    const float* b22  = (const float*)d_in[10];
    const float* W32  = (const float*)d_in[11];
    const float* b32  = (const float*)d_in[12];
    // d_in[13] = sgn (scalar, unused by the forward pass)
    int B = in_sizes[0] / 8;
    float* out = (float*)d_out;
    dim3 block(64);
    dim3 grid((B + 63) / 64);
    hipLaunchKernelGGL(barriernet_kernel, grid, block, 0, stream,
                       x, mean, stdv, W1, b1, W21, b21, W31, b31,
                       W22, b22, W32, b32, out, B);
}

// Round 3
// 146.296 us; speedup vs baseline: 4.5723x; 4.5723x over previous
//
#include <hip/hip_runtime.h>
#include <math.h>

// BarrierNet fused forward, MFMA edition.
// Layer1 (8->256) per-lane VALU directly into A-fragments; heads (256->128)
// via v_mfma_f32_16x16x32_bf16 with pre-swizzled bf16 B-fragments in d_ws;
// fused bias+relu+W3 epilogue; closed-form 2D QP per row.

typedef unsigned int u32;
typedef unsigned short u16;
typedef __attribute__((ext_vector_type(8))) short short8;   // 8 bf16 = 4 VGPR (MFMA A/B)
typedef __attribute__((ext_vector_type(4))) float f32x4;    // MFMA C/D
typedef __attribute__((ext_vector_type(4))) u32 u32x4;      // 16B raw load

union Frag { short8 v; u32 u[4]; u32x4 q; };

__device__ __forceinline__ u16 f2bf(float f) {
    union { float f; u32 i; } v; v.f = f;
    u32 b = v.i;
    return (u16)((b + 0x7fffu + ((b >> 16) & 1u)) >> 16);   // RNE
}
__device__ __forceinline__ u32 packbf(float a, float b) {
    return (u32)f2bf(a) | ((u32)f2bf(b) << 16);
}

// ---------- prep: swizzle W2{1,2} (f32 [128][256]) into bf16 B-fragments ----------
// frag index f = head*4096 + nt*512 + ks*64 + lane ; content j=0..7:
//   W2h[n = nt*16 + (lane&15)][k = ks*32 + (lane>>4)*8 + j]
__global__ __launch_bounds__(256)
void prep_kernel(const float* __restrict__ W21, const float* __restrict__ W22,
                 u32* __restrict__ ws)
{
    int idx  = blockIdx.x * 256 + threadIdx.x;      // 0..8191
    int lane = idx & 63;
    int ks   = (idx >> 6) & 7;
    int nt   = (idx >> 9) & 7;
    int head = idx >> 12;
    const float* W = head ? W22 : W21;
    int n  = nt * 16 + (lane & 15);
    int k0 = ks * 32 + (lane >> 4) * 8;
    const float* s = W + n * 256 + k0;
    u32x4 o;
    o.x = packbf(s[0], s[1]);
    o.y = packbf(s[2], s[3]);
    o.z = packbf(s[4], s[5]);
    o.w = packbf(s[6], s[7]);
    ((u32x4*)ws)[idx] = o;
}

// ---------- main ----------
__global__ __launch_bounds__(256, 1)
void barriernet_kernel(const float* __restrict__ x,      // [B,8]
                       const float* __restrict__ meanp,  // [8]
                       const float* __restrict__ stdp,   // [8]
                       const float* __restrict__ W1,     // [256][8]
                       const float* __restrict__ b1,     // [256]
                       const float* __restrict__ b21,    // [128]
                       const float* __restrict__ W31,    // [2][128]
                       const float* __restrict__ b31,    // [2]
                       const float* __restrict__ b22,    // [128]
                       const float* __restrict__ W32,    // [2][128]
                       const float* __restrict__ b32,    // [2]
                       const u32* __restrict__ wsB,      // swizzled bf16 B-frags
                       float* __restrict__ out, int Btot)
{
    const int tid  = threadIdx.x;
    const int wave = tid >> 6;
    const int lane = tid & 63;
    const int q    = lane >> 4;    // quad
    const int m    = lane & 15;
    const int rowBase = blockIdx.x * 256 + wave * 64;

    __shared__ float lds_p[4][64][4];

    // ---- layer 1: compute hid directly as MFMA A-fragments (bf16 packed)
    // A[mt][ks]: lane holds A[m][k = ks*32 + q*8 + j], row = rowBase + mt*16 + m
    Frag A[4][8];
    #pragma unroll
    for (int mt = 0; mt < 4; ++mt) {
        int R = rowBase + mt * 16 + m;
        float xf[8];
        const float* xp = x + (R < Btot ? R : 0) * 8;
        #pragma unroll
        for (int c = 0; c < 8; ++c) xf[c] = xp[c];
        #pragma unroll
        for (int ks = 0; ks < 8; ++ks) {
            int kb = ks * 32 + q * 8;
            float h[8];
            #pragma unroll
            for (int j = 0; j < 8; ++j) {
                const float* w = W1 + (kb + j) * 8;
                float a = b1[kb + j];
                #pragma unroll
                for (int c = 0; c < 8; ++c) a = fmaf(w[c], xf[c], a);
                h[j] = fmaxf(a, 0.f);
            }
            #pragma unroll
            for (int t = 0; t < 4; ++t)
                A[mt][ks].u[t] = packbf(h[2 * t], h[2 * t + 1]);
        }
    }

    // ---- two heads via MFMA
    #pragma unroll 1
    for (int head = 0; head < 2; ++head) {
        const u32x4* Bbase = (const u32x4*)wsB + head * 4096;
        const float* b2 = head ? b22 : b21;
        const float* W3 = head ? W32 : W31;
        const float* b3 = head ? b32 : b31;

        float pr0[4][4], pr1[4][4];
        #pragma unroll
        for (int mt = 0; mt < 4; ++mt)
            #pragma unroll
            for (int rg = 0; rg < 4; ++rg) { pr0[mt][rg] = 0.f; pr1[mt][rg] = 0.f; }

        #pragma unroll
        for (int nt = 0; nt < 8; ++nt) {
            Frag Bf[8];
            #pragma unroll
            for (int ks = 0; ks < 8; ++ks)
                Bf[ks].q = Bbase[nt * 512 + ks * 64 + lane];
            int col = nt * 16 + m;
            float b2c = b2[col];
            float w0c = W3[col];
            float w1c = W3[128 + col];
            #pragma unroll
            for (int mt = 0; mt < 4; ++mt) {
                f32x4 acc = {0.f, 0.f, 0.f, 0.f};
                #pragma unroll
                for (int ks = 0; ks < 8; ++ks)
                    acc = __builtin_amdgcn_mfma_f32_16x16x32_bf16(A[mt][ks].v, Bf[ks].v, acc, 0, 0, 0);
                // acc[rg] = D[row = q*4+rg (+mt*16)][col]
                #pragma unroll
                for (int rg = 0; rg < 4; ++rg) {
                    float rv = fmaxf(acc[rg] + b2c, 0.f);
                    pr0[mt][rg] = fmaf(rv, w0c, pr0[mt][rg]);
                    pr1[mt][rg] = fmaf(rv, w1c, pr1[mt][rg]);
                }
            }
        }

        // reduce over the 16 column-lanes (m = 0..15 within quad group)
        #pragma unroll
        for (int mt = 0; mt < 4; ++mt) {
            #pragma unroll
            for (int rg = 0; rg < 4; ++rg) {
                float v0 = pr0[mt][rg], v1 = pr1[mt][rg];
                #pragma unroll
                for (int off = 1; off < 16; off <<= 1) {
                    v0 += __shfl_xor(v0, off, 64);
                    v1 += __shfl_xor(v1, off, 64);
                }
                pr0[mt][rg] = v0; pr1[mt][rg] = v1;
            }
        }
        if (m == 0) {
            #pragma unroll
            for (int mt = 0; mt < 4; ++mt) {
                #pragma unroll
                for (int rg = 0; rg < 4; ++rg) {
                    int row = mt * 16 + q * 4 + rg;
                    float a0 = pr0[mt][rg] + b3[0];
                    float a1 = pr1[mt][rg] + b3[1];
                    if (head == 0) {
                        lds_p[wave][row][0] = a0;
                        lds_p[wave][row][1] = a1;
                    } else {
                        lds_p[wave][row][2] = 4.f / (1.f + expf(-a0));
                        lds_p[wave][row][3] = 4.f / (1.f + expf(-a1));
                    }
                }
            }
        }
    }
    __syncthreads();

    // ---- QP per row: lane handles row = lane
    int R = rowBase + lane;
    float p0 = lds_p[wave][lane][0];
    float p1 = lds_p[wave][lane][1];
    float s0 = lds_p[wave][lane][2];
    float s1 = lds_p[wave][lane][3];

    float xf[8];
    const float* xp = x + (R < Btot ? R : 0) * 8;
    #pragma unroll
    for (int c = 0; c < 8; ++c) xf[c] = fmaf(xp[c], stdp[c], meanp[c]);
    float px = xf[0], py = xf[1], th = xf[2], v = xf[3];
    float ox = xf[4], oy = xf[5], oth = xf[6], ov = xf[7];

    float st = sinf(th),  ct = cosf(th);
    float so = sinf(oth), co = cosf(oth);
    float vs = v * st, vc = v * ct;
    float sps = s0 + s1, ss = s0 * s1;

    const float obx[8] = { 10.f, 7.07106781186547524f, 6.123234e-16f, -7.07106781186547524f,
                          -10.f, -7.07106781186547524f, -1.8369702e-15f, 7.07106781186547524f };
    const float oby[8] = { 0.f, 7.07106781186547524f, 10.f, 7.07106781186547524f,
                           1.2246468e-15f, -7.07106781186547524f, -10.f, -7.07106781186547524f };
    float Gx[9], Gy[9], hc[9], tol[9];
    float Lf2b = 2.f * v * v;
    #pragma unroll
    for (int k = 0; k < 8; ++k) {
        float dx = px - obx[k], dy = py - oby[k];
        float bar  = dx * dx + dy * dy - 0.64f;
        float bdot = 2.f * dx * vc + 2.f * dy * vs;
        Gx[k] = 2.f * dx * vs - 2.f * dy * vc;
        Gy[k] = -(2.f * dx * ct + 2.f * dy * st);
        hc[k] = Lf2b + sps * bdot + ss * bar;
    }
    {
        float dxo = px - ox, dyo = py - oy;
        float bar_o  = dxo * dxo + dyo * dyo - 0.25f;
        float bdot_o = 2.f * dxo * (vc - ov * co) + 2.f * dyo * (vs - ov * so);
        float Lf2b_o = 2.f * (v * v + ov * ov + 2.f * v * ov * cosf(th - oth));
        Gx[8] = 2.f * dxo * vs - 2.f * dyo * vc;
        Gy[8] = -(2.f * dxo * ct + 2.f * dyo * st);
        hc[8] = Lf2b_o + sps * bdot_o + ss * bar_o;
    }
    #pragma unroll
    for (int k = 0; k < 9; ++k) tol[k] = 1e-6f * (1.f + fabsf(hc[k]));

    float bzx = -p0, bzy = -p1;
    float bobj = INFINITY;
    {
        float zx = -p0, zy = -p1;
        bool f = true;
        #pragma unroll
        for (int k = 0; k < 9; ++k) f = f && (zx * Gx[k] + zy * Gy[k] <= hc[k] + tol[k]);
        if (f) bobj = 0.5f * (zx * zx + zy * zy) + zx * p0 + zy * p1;
    }
    #pragma unroll
    for (int i = 0; i < 9; ++i) {
        float gg  = Gx[i] * Gx[i] + Gy[i] * Gy[i];
        float lam = (-(Gx[i] * p0 + Gy[i] * p1) - hc[i]) / (gg + 1e-12f);
        float zx = -p0 - lam * Gx[i];
        float zy = -p1 - lam * Gy[i];
        bool ok = (lam >= -1e-8f);
        #pragma unroll
        for (int k = 0; k < 9; ++k) ok = ok && (zx * Gx[k] + zy * Gy[k] <= hc[k] + tol[k]);
        float obj = 0.5f * (zx * zx + zy * zy) + zx * p0 + zy * p1;
        if (ok && obj < bobj) { bobj = obj; bzx = zx; bzy = zy; }
    }
    #pragma unroll
    for (int i = 0; i < 8; ++i) {
        #pragma unroll
        for (int j = i + 1; j < 9; ++j) {
            float det = Gx[i] * Gy[j] - Gy[i] * Gx[j];
            bool dok = fabsf(det) > 1e-9f;
            float ds = dok ? det : 1.0f;
            float zx = (hc[i] * Gy[j] - hc[j] * Gy[i]) / ds;
            float zy = (Gx[i] * hc[j] - Gx[j] * hc[i]) / ds;
            float rx = -(zx + p0), ry = -(zy + p1);
            float li = (Gy[j] * rx - Gx[j] * ry) / ds;
            float lj = (Gx[i] * ry - Gy[i] * rx) / ds;
            bool ok = dok && (li >= -1e-8f) && (lj >= -1e-8f);
            #pragma unroll
            for (int k = 0; k < 9; ++k) ok = ok && (zx * Gx[k] + zy * Gy[k] <= hc[k] + tol[k]);
            float obj = 0.5f * (zx * zx + zy * zy) + zx * p0 + zy * p1;
            if (ok && obj < bobj) { bobj = obj; bzx = zx; bzy = zy; }
        }
    }

    if (R < Btot) {
        out[2 * R]     = bzx;
        out[2 * R + 1] = bzy;
    }
}

extern "C" void kernel_launch(void* const* d_in, const int* in_sizes, int n_in,
                              void* d_out, int out_size, void* d_ws, size_t ws_size,
                              hipStream_t stream) {
    const float* x    = (const float*)d_in[0];
    const float* mean = (const float*)d_in[1];
    const float* stdv = (const float*)d_in[2];
    const float* W1   = (const float*)d_in[3];
    const float* b1   = (const float*)d_in[4];
    const float* W21  = (const float*)d_in[5];
    const float* b21  = (const float*)d_in[6];
    const float* W31  = (const float*)d_in[7];
    const float* b31  = (const float*)d_in[8];
    const float* W22  = (const float*)d_in[9];
    const float* b22  = (const float*)d_in[10];
    const float* W32  = (const float*)d_in[11];
    const float* b32  = (const float*)d_in[12];
    int B = in_sizes[0] / 8;
    float* out = (float*)d_out;
    u32* ws = (u32*)d_ws;

    hipLaunchKernelGGL(prep_kernel, dim3(32), dim3(256), 0, stream, W21, W22, ws);

    int blocks = (B + 255) / 256;
    hipLaunchKernelGGL(barriernet_kernel, dim3(blocks), dim3(256), 0, stream,
                       x, mean, stdv, W1, b1, b21, W31, b31, b22, W32, b32,
                       ws, out, B);
}